// Round 5
// baseline (556.632 us; speedup 1.0000x reference)
//
#include <hip/hip_runtime.h>

#define TSTEPS 1023
#define GAMMA  (0.01f / 32.0f)   // LR * dL/dy scale: 2/(64*2) folded
#define GAMMA2 (GAMMA * GAMMA)
#define EPSV   1e-5f

// workspace layout (float offsets)
#define WS_HS 0       // 64*64 hs table
#define WS_G  4096    // 64*64 PRE-SCALED gram: Gs = GAMMA*G + GAMMA
#define WS_Z0 8192    // 64*16 initial Ztilde = hs@w1 + b1
#define WS_M  9216    // 16*16 W2 Gram: M0 = w2 @ w2^T

typedef float v2f __attribute__((ext_vector_type(2)));
typedef unsigned int v2u __attribute__((ext_vector_type(2)));

template<int CTRL>
__device__ __forceinline__ float dppmov(float x) {
    return __int_as_float(__builtin_amdgcn_update_dpp(0, __float_as_int(x), CTRL, 0xF, 0xF, true));
}
__device__ __forceinline__ v2u swap16(float a, float b) {
    return __builtin_amdgcn_permlane16_swap(__float_as_uint(a), __float_as_uint(b), false, false);
}
__device__ __forceinline__ v2u swap32(float a, float b) {
    return __builtin_amdgcn_permlane32_swap(__float_as_uint(a), __float_as_uint(b), false, false);
}
__device__ __forceinline__ float rlane(float v, int sl) {
    return __int_as_float(__builtin_amdgcn_readlane(__float_as_int(v), sl));
}
#define U2F(x) __uint_as_float(x)

// ---------------- kernel A: hs table (per-token embed->FFN->LN), 64 blocks ----------------
__global__ void hs_kernel(const float* __restrict__ embed,
                          const float* __restrict__ ffw1, const float* __restrict__ ffb1,
                          const float* __restrict__ ffw2, const float* __restrict__ ffb2,
                          const float* __restrict__ lng,  const float* __restrict__ lnb,
                          float* __restrict__ ws) {
    __shared__ float e[64];
    __shared__ float a1[128];
    int w = blockIdx.x;
    int tid = threadIdx.x;
    if (tid < 64) e[tid] = embed[w * 64 + tid];
    __syncthreads();
    float z1 = ffb1[tid];
    for (int x = 0; x < 64; ++x) z1 += e[x] * ffw1[x * 128 + tid];
    a1[tid] = fmaxf(z1, 0.0f);
    __syncthreads();
    if (tid < 64) {
        float f = ffb2[tid];
        for (int i = 0; i < 128; ++i) f += a1[i] * ffw2[i * 64 + tid];
        float hv = e[tid] + f;
        float s = hv;
#pragma unroll
        for (int m = 32; m >= 1; m >>= 1) s += __shfl_xor(s, m);
        float mu = s * (1.0f / 64.0f);
        float dv = hv - mu;
        float vs = dv * dv;
#pragma unroll
        for (int m = 32; m >= 1; m >>= 1) vs += __shfl_xor(vs, m);
        float rstd = 1.0f / sqrtf(vs * (1.0f / 64.0f) + EPSV);
        ws[WS_HS + w * 64 + tid] = dv * rstd * lng[tid] + lnb[tid];
    }
}

// ---------------- kernel B: pre-scaled Gram + Ztilde0, 64 blocks ----------------
__global__ void gz_kernel(const float* __restrict__ w1, const float* __restrict__ b1,
                          float* __restrict__ ws) {
    __shared__ float row[64];
    int w = blockIdx.x, tid = threadIdx.x;
    row[tid] = ws[WS_HS + w * 64 + tid];
    __syncthreads();
    float g = 0.0f;
    for (int x = 0; x < 64; ++x) g += row[x] * ws[WS_HS + tid * 64 + x];
    ws[WS_G + w * 64 + tid] = GAMMA * g + GAMMA;      // pre-scaled
    if (tid < 16) {
        float z = b1[tid];
        for (int x = 0; x < 64; ++x) z += row[x] * w1[x * 16 + tid];
        ws[WS_Z0 + w * 16 + tid] = z;
    }
}

// ---------------- kernel C: W2 Gram M0[j][k] = sum_h w2[j,h]w2[k,h], 1 block x 256 ----------------
__global__ void m0_kernel(const float* __restrict__ w2, float* __restrict__ ws) {
    int j = threadIdx.x >> 4, k = threadIdx.x & 15;
    float acc = 0.0f;
    for (int h = 0; h < 64; ++h) acc += w2[j * 64 + h] * w2[k * 64 + h];
    ws[WS_M + threadIdx.x] = acc;
}

// ---------------- main kernel: 4-wave j-split TTT scan, GRAM-MAINTAINED dz ----------------
// Identity: dz = mask.(W2 d) = mask.(M a + m - s), M = W2W2^T, m = W2 b2, s = W2 v.
// -> dz has NO dependence on the exchanged y. Post-exchange critical chain is only
// d -> W2 update -> next ypart (~12 ops). All reduces run in the exchange shadow:
//   s_{t+1} = reduceS(W2_{t+1} o vnext)      (inputs known pre-barrier)
//   u_t = M_t a_t: M lane-distributed (lane l = M[4wv+(l>>4), l&15]); a_t published
//     as 4 floats/wave at the same barrier; 1 mul + row_ror 1/2/4/8 + 4 readlane.
// Rank-1 recurrences (exact algebra of the actual updates):
//   c = W2 d = (Ma+m) - s (free); M+ = M - g(ac^T + ca^T) + g^2|d|^2 aa^T;
//   m+ = m - gc - g(d.b2)a + g^2|d|^2 a.  |d|^2 & d.b2: joint DPP butterfly
//   post-d with a FULL STEP of slack (consumed by next step's M+/m+).
// Publishes per wave per step: ypart(64), a-slice(4), c-slice(4); wave0: d.b2(1).
// Z stays register-resident (row=lane), E via readlane; slots permuted (X=2*b0)
// for the cheap reduceS; M/u/publish use LOGICAL order (LDS round-trip converts).
struct TTT4Smem {
    float hs[4096];
    float Gs[4096];
    int   sq[2048];                 // unguarded prefetch reads sq[2048..2049] -> land in ybuf (harmless)
    float ybuf[2][4][64];           // [parity][wave][lane] y-partial exchange
    float abuf[2][16];              // published a_t (logical order)
    float cbuf[2][16];              // published c_{t-1} (logical order)
    float dbuf[2];                  // published d.b2 (wave0)
    float ctxp[4][64];              // final ctx partials
};

// unmasked column-sum reduce: out[j-slots] = sum_h p2[j-slot][h] (permuted slot order)
__device__ __forceinline__ void reduceS(const v2f* p2, v2f* out) {
    float q0 = p2[0].x + dppmov<0xB1>(p2[1].x);
    float q1 = p2[0].y + dppmov<0xB1>(p2[1].y);
    v2u f01 = swap16(q0, q1);
    float T = U2F(f01[0]) + U2F(f01[1]);
    v2u g01 = swap32(T, T);
    T = U2F(g01[0]) + U2F(g01[1]);
    T = T + dppmov<0x122>(T);
    T = T + dppmov<0x124>(T);
    T = T + dppmov<0x128>(T);
    v2u u01 = swap16(T, T);
    const float A0 = U2F(u01[0]);
    const float A1 = U2F(u01[1]);
    out[0] = {A0, A1};
    out[1] = {dppmov<0xB1>(A0), dppmov<0xB1>(A1)};
}

// logical-order extract for publish lanes 0..3 (lane L -> logical j = 4wv+L; slot = L ^ 2*(L&1))
__device__ __forceinline__ float pubsel(const v2f* x2, int lane) {
    float odd  = (lane & 2) ? x2[0].y : x2[1].y;   // L=1->slot3, L=3->slot1
    float even = (lane & 2) ? x2[1].x : x2[0].x;   // L=0->slot0, L=2->slot2
    return (lane & 1) ? odd : even;
}

__launch_bounds__(256, 1)
__global__ void ttt_kernel(const int* __restrict__ seq,
                           const float* __restrict__ w2, const float* __restrict__ b2i,
                           const float* __restrict__ outw, const float* __restrict__ outb,
                           const float* __restrict__ ws, float* __restrict__ out) {
    __shared__ TTT4Smem sm;

    const int b    = blockIdx.x;
    const int tid  = threadIdx.x;
    const int wv   = tid >> 6;
    const int lane = tid & 63;
    const int b0   = lane & 1;
    const int X    = b0 << 1;              // slot xor: logical j = 4*wv + (slot ^ X)
    const bool pb  = (b0 != 0);
    const bool wv0 = (wv == 0);

    {   // vectorized staging (256 threads)
        float4*       hv = (float4*)sm.hs;
        const float4* sv = (const float4*)(ws + WS_HS);
#pragma unroll
        for (int m = 0; m < 4; ++m) hv[m * 256 + tid] = sv[m * 256 + tid];
        float4*       gv = (float4*)sm.Gs;
        const float4* gs = (const float4*)(ws + WS_G);
#pragma unroll
        for (int m = 0; m < 4; ++m) gv[m * 256 + tid] = gs[m * 256 + tid];
        int4*       qv = (int4*)sm.sq;
        const int4* qs = (const int4*)(seq + b * 2048);
#pragma unroll
        for (int m = 0; m < 2; ++m) qv[m * 256 + tid] = qs[m * 256 + tid];
    }

    // Z state: row = lane, this wave's 4 j-columns, LOGICAL order, registers only
    v2f Zv[2];
    {
        const float4 z0 = *(const float4*)(ws + WS_Z0 + lane * 16 + 4 * wv);
        Zv[0] = {z0.x, z0.y};
        Zv[1] = {z0.z, z0.w};
    }

    // W2 in permuted slot order for this wave's j-slice
    v2f W2p[2];
#pragma unroll
    for (int i = 0; i < 2; ++i) {
        v2f w;
        w.x = w2[(4 * wv + ((2 * i) ^ X)) * 64 + lane];
        w.y = w2[(4 * wv + ((2 * i + 1) ^ X)) * 64 + lane];
        W2p[i] = w;
    }
    // M rows (logical layout): lane l holds M[4wv + (l>>4), l&15]
    float Mreg = ws[WS_M + (4 * wv + (lane >> 4)) * 16 + (lane & 15)];
    const float bful = b2i[lane];             // full b2 (for m0 init)
    float ybias = wv0 ? bful : 0.0f;          // b2 lives in wave0's y-partial only
    const float gma = wv0 ? GAMMA : 0.0f;
    __syncthreads();

    // z2 init: row sq[0] broadcast from registers via readlane, permuted slots
    int tk = sm.sq[0];
    v2f z2[2];
    {
        const int stk = __builtin_amdgcn_readfirstlane(tk);
        const float e0 = rlane(Zv[0].x, stk);
        const float e1 = rlane(Zv[0].y, stk);
        const float e2 = rlane(Zv[1].x, stk);
        const float e3 = rlane(Zv[1].y, stk);
        z2[0] = { pb ? e2 : e0, pb ? e3 : e1 };
        z2[1] = { pb ? e0 : e2, pb ? e1 : e3 };
    }
    float vv = sm.hs[sm.sq[1] * 64 + lane];

    // m_0 = W2 b2, s_0 = W2 v_0 (permuted slots, shadow reduces)
    v2f m2[2], s2[2];
    {
        const v2f bb = {bful, bful};
        v2f p0[2] = { W2p[0] * bb, W2p[1] * bb };
        reduceS(p0, m2);
        const v2f vs0 = {vv, vv};
        v2f p1[2] = { W2p[0] * vs0, W2p[1] * vs0 };
        reduceS(p1, s2);
    }

    // carries (step -1): zero so first M/m updates are no-ops
    float avp = 0.0f, ajp = 0.0f, ddv = 0.0f, db2pub = 0.0f;
    v2f cs_prev[2] = {{0.0f, 0.0f}, {0.0f, 0.0f}};
    v2f as_prev[2] = {{0.0f, 0.0f}, {0.0f, 0.0f}};

    int2 pairT  = *(const int2*)(sm.sq + 2);
    int2 pairT1 = *(const int2*)(sm.sq + 4);

    const v2f zero2 = {0.0f, 0.0f};

    // main loop: steps 0..1021 (last step peeled)
#pragma unroll 2
    for (int t = 0; t < TSTEPS - 1; ++t) {
        const int tkn = pairT.x;
        const int tvn = pairT.y;
        const int par = t & 1;

        // ---- pre-barrier: forward + publishes ----
        v2f a2[2];
        a2[0] = __builtin_elementwise_max(z2[0], zero2);
        a2[1] = __builtin_elementwise_max(z2[1], zero2);
        v2f accv = a2[0] * W2p[0] + a2[1] * W2p[1];
        const float ypart = ybias + accv.x + accv.y;

        sm.ybuf[par][wv][lane] = ypart;
        if (lane < 4) {
            sm.abuf[par][4 * wv + lane] = pubsel(a2, lane);       // a_t
            sm.cbuf[par][4 * wv + lane] = pubsel(cs_prev, lane);  // c_{t-1}
        }
        if (wv0 && lane == 0) sm.dbuf[par] = db2pub;              // d_{t-1}.b2_{t-1}
        __syncthreads();

        // ---- reads ----
        const float y0 = sm.ybuf[par][0][lane];
        const float y1 = sm.ybuf[par][1][lane];
        const float y2 = sm.ybuf[par][2][lane];
        const float y3 = sm.ybuf[par][3][lane];
        const float av   = sm.abuf[par][lane & 15];               // a_t[k]
        const float ajn  = sm.abuf[par][4 * wv + (lane >> 4)];    // a_t[j]
        const float ck   = sm.cbuf[par][lane & 15];               // c_{t-1}[k]
        const float cjn  = sm.cbuf[par][4 * wv + (lane >> 4)];    // c_{t-1}[j]
        const float db2s = sm.dbuf[par];
        const float vnext = sm.hs[tvn * 64 + lane];
        const float cr = sm.Gs[tk * 64 + lane];     // pre-scaled gamma*(G+1), row tk
        const int2 pairT2 = *(const int2*)(sm.sq + 2 * t + 6);  // t=1021 reads ybuf: unused

        // ---- M_t = M_{t-1} - g(a c^T + c a^T) + g^2|d|^2 a a^T  (all step t-1 quantities) ----
        const float t1 = ddv * GAMMA2;
        const float Aj = t1 * ajp - GAMMA * cjn;
        Mreg = Mreg + avp * Aj - (GAMMA * ajp) * ck;

        // ---- m_t = m_{t-1} - g c - g(d.b2) a + g^2|d|^2 a ----
        const float S = t1 - GAMMA * db2s;
        const v2f Sv = {S, S};
        const v2f Gm = {GAMMA, GAMMA};
        m2[0] = m2[0] - Gm * cs_prev[0] + Sv * as_prev[0];
        m2[1] = m2[1] - Gm * cs_prev[1] + Sv * as_prev[1];

        // ---- u_t = M_t a_t: lane-product + row_ror reduce over k (16-group) ----
        float ur = Mreg * av;
        ur += dppmov<0x121>(ur);
        ur += dppmov<0x122>(ur);
        ur += dppmov<0x124>(ur);
        ur += dppmov<0x128>(ur);
        const float uj0 = rlane(ur, 0);
        const float uj1 = rlane(ur, 16);
        const float uj2 = rlane(ur, 32);
        const float uj3 = rlane(ur, 48);
        const v2f Ulo = {uj0, uj1};
        const v2f Uhi = {uj2, uj3};

        // ---- c_t = (M a + m) - s = W2_t d_t ; dz = mask.c ----
        v2f c2[2];
        c2[0] = (pb ? Uhi : Ulo) + m2[0] - s2[0];
        c2[1] = (pb ? Ulo : Uhi) + m2[1] - s2[1];
        v2f dz2[2];
        dz2[0] = { a2[0].x > 0.0f ? c2[0].x : 0.0f, a2[0].y > 0.0f ? c2[0].y : 0.0f };
        dz2[1] = { a2[1].x > 0.0f ? c2[1].x : 0.0f, a2[1].y > 0.0f ? c2[1].y : 0.0f };

        // ---- E (register-Z row tkn) + cz ----
        const int stkn = __builtin_amdgcn_readfirstlane(tkn);
        const float e0 = rlane(Zv[0].x, stkn);
        const float e1 = rlane(Zv[0].y, stkn);
        const float e2 = rlane(Zv[1].x, stkn);
        const float e3 = rlane(Zv[1].y, stkn);
        const v2f E0 = { pb ? e2 : e0, pb ? e3 : e1 };
        const v2f E1 = { pb ? e0 : e2, pb ? e1 : e3 };
        const float cz = rlane(cr, stkn);

        // ---- z2_{t+1} (table lag covered by cz term, as before) ----
        const v2f cz2 = {cz, cz};
        z2[0] = E0 - cz2 * dz2[0];
        z2[1] = E1 - cz2 * dz2[1];

        // ---- d_t (fixed tree), W2/b2 update -- the ONLY post-exchange chain ----
        const float d = ((y0 + y1) + (y2 + y3)) - vv;
        const float Qv = d * ybias;               // d.b2 partial (pre-update b2)
        const float sd = GAMMA * d;
        ybias -= gma * d;
        const v2f sd2 = {sd, sd};
        W2p[0] = W2p[0] - sd2 * a2[0];
        W2p[1] = W2p[1] - sd2 * a2[1];

        // ---- joint butterfly: |d|^2 and d.b2 (one step of slack) ----
        float P = d * d, Q = Qv;
        P += dppmov<0xB1>(P);  Q += dppmov<0xB1>(Q);
        P += dppmov<0x4E>(P);  Q += dppmov<0x4E>(Q);
        P += dppmov<0x124>(P); Q += dppmov<0x124>(Q);
        P += dppmov<0x128>(P); Q += dppmov<0x128>(Q);
        v2u pq = swap16(P, Q);
        float T2 = U2F(pq[0]) + U2F(pq[1]);
        v2u pq2 = swap32(T2, T2);
        T2 = U2F(pq2[0]) + U2F(pq2[1]);           // b4=0 lanes: sum d^2 ; b4=1: sum d.b2
        const float ddn   = rlane(T2, 0);
        const float db2n  = rlane(T2, 16);

        // ---- s_{t+1} = W2_{t+1} v_{t+1} (shadow reduce, post-update W2) ----
        {
            const v2f vs2 = {vnext, vnext};
            v2f ps[2] = { W2p[0] * vs2, W2p[1] * vs2 };
            reduceS(ps, s2);
        }

        // ---- prompt register-Z update (logical order) ----
        const v2f dzl0 = pb ? dz2[1] : dz2[0];
        const v2f dzl1 = pb ? dz2[0] : dz2[1];
        const v2f cr2 = {cr, cr};
        Zv[0] = Zv[0] - cr2 * dzl0;
        Zv[1] = Zv[1] - cr2 * dzl1;

        // ---- carries ----
        avp = av; ajp = ajn;
        cs_prev[0] = c2[0]; cs_prev[1] = c2[1];
        as_prev[0] = a2[0]; as_prev[1] = a2[1];
        ddv = ddn; db2pub = db2n;

        vv = vnext;
        tk = tkn;
        pairT = pairT1;
        pairT1 = pairT2;
    }

    // ---- peeled final step (t = 1022, par = 0): tkn = query token sq[2047] ----
    {
        const int tkn = pairT.y;                  // pairT = {sq[2046], sq[2047]}
        v2f a2[2];
        a2[0] = __builtin_elementwise_max(z2[0], zero2);
        a2[1] = __builtin_elementwise_max(z2[1], zero2);
        v2f accv = a2[0] * W2p[0] + a2[1] * W2p[1];
        const float ypart = ybias + accv.x + accv.y;

        sm.ybuf[0][wv][lane] = ypart;
        if (lane < 4) {
            sm.abuf[0][4 * wv + lane] = pubsel(a2, lane);
            sm.cbuf[0][4 * wv + lane] = pubsel(cs_prev, lane);
        }
        if (wv0 && lane == 0) sm.dbuf[0] = db2pub;
        __syncthreads();

        const float y0 = sm.ybuf[0][0][lane];
        const float y1 = sm.ybuf[0][1][lane];
        const float y2 = sm.ybuf[0][2][lane];
        const float y3 = sm.ybuf[0][3][lane];
        const float av   = sm.abuf[0][lane & 15];
        const float ajn  = sm.abuf[0][4 * wv + (lane >> 4)];
        const float ck   = sm.cbuf[0][lane & 15];
        const float cjn  = sm.cbuf[0][4 * wv + (lane >> 4)];
        const float db2s = sm.dbuf[0];
        const float cr = sm.Gs[tk * 64 + lane];

        const float t1 = ddv * GAMMA2;
        const float Aj = t1 * ajp - GAMMA * cjn;
        Mreg = Mreg + avp * Aj - (GAMMA * ajp) * ck;

        const float S = t1 - GAMMA * db2s;
        const v2f Sv = {S, S};
        const v2f Gm = {GAMMA, GAMMA};
        m2[0] = m2[0] - Gm * cs_prev[0] + Sv * as_prev[0];
        m2[1] = m2[1] - Gm * cs_prev[1] + Sv * as_prev[1];

        float ur = Mreg * av;
        ur += dppmov<0x121>(ur);
        ur += dppmov<0x122>(ur);
        ur += dppmov<0x124>(ur);
        ur += dppmov<0x128>(ur);
        const float uj0 = rlane(ur, 0);
        const float uj1 = rlane(ur, 16);
        const float uj2 = rlane(ur, 32);
        const float uj3 = rlane(ur, 48);
        const v2f Ulo = {uj0, uj1};
        const v2f Uhi = {uj2, uj3};

        v2f c2[2];
        c2[0] = (pb ? Uhi : Ulo) + m2[0] - s2[0];
        c2[1] = (pb ? Ulo : Uhi) + m2[1] - s2[1];
        v2f dz2[2];
        dz2[0] = { a2[0].x > 0.0f ? c2[0].x : 0.0f, a2[0].y > 0.0f ? c2[0].y : 0.0f };
        dz2[1] = { a2[1].x > 0.0f ? c2[1].x : 0.0f, a2[1].y > 0.0f ? c2[1].y : 0.0f };

        const int stkn = __builtin_amdgcn_readfirstlane(tkn);
        const float e0 = rlane(Zv[0].x, stkn);    // Zv current through step 1021
        const float e1 = rlane(Zv[0].y, stkn);
        const float e2 = rlane(Zv[1].x, stkn);
        const float e3 = rlane(Zv[1].y, stkn);
        const v2f E0 = { pb ? e2 : e0, pb ? e3 : e1 };
        const v2f E1 = { pb ? e0 : e2, pb ? e1 : e3 };
        const float cz = rlane(cr, stkn);

        const v2f cz2 = {cz, cz};
        z2[0] = E0 - cz2 * dz2[0];
        z2[1] = E1 - cz2 * dz2[1];

        const float d = ((y0 + y1) + (y2 + y3)) - vv;
        const float sd = GAMMA * d;
        ybias -= gma * d;
        const v2f sd2 = {sd, sd};
        W2p[0] = W2p[0] - sd2 * a2[0];
        W2p[1] = W2p[1] - sd2 * a2[1];
    }

    // ---- final eval: ctx partial per wave, combine, then out matvec ----
    {
        v2f acc = __builtin_elementwise_max(z2[0], zero2) * W2p[0]
                + __builtin_elementwise_max(z2[1], zero2) * W2p[1];
        sm.ctxp[wv][lane] = ybias + acc.x + acc.y;
    }
    __syncthreads();
    if (wv0) {
        float o = outb[lane];
        for (int hh = 0; hh < 64; ++hh)
            o += (sm.ctxp[0][hh] + sm.ctxp[1][hh] + sm.ctxp[2][hh] + sm.ctxp[3][hh])
                 * outw[hh * 64 + lane];
        out[b * 64 + lane] = o;
    }
}

// ---------------- launcher ----------------
extern "C" void kernel_launch(void* const* d_in, const int* in_sizes, int n_in,
                              void* d_out, int out_size, void* d_ws, size_t ws_size,
                              hipStream_t stream) {
    const int*   seq   = (const int*)d_in[0];
    const float* embed = (const float*)d_in[1];
    const float* ffw1  = (const float*)d_in[2];
    const float* ffb1  = (const float*)d_in[3];
    const float* ffw2  = (const float*)d_in[4];
    const float* ffb2  = (const float*)d_in[5];
    const float* lng   = (const float*)d_in[6];
    const float* lnb   = (const float*)d_in[7];
    const float* w1    = (const float*)d_in[8];
    const float* b1    = (const float*)d_in[9];
    const float* w2    = (const float*)d_in[10];
    const float* b2    = (const float*)d_in[11];
    const float* outw  = (const float*)d_in[12];
    const float* outb  = (const float*)d_in[13];
    float* ws  = (float*)d_ws;
    float* out = (float*)d_out;

    hipLaunchKernelGGL(hs_kernel, dim3(64), dim3(128), 0, stream,
                       embed, ffw1, ffb1, ffw2, ffb2, lng, lnb, ws);
    hipLaunchKernelGGL(gz_kernel, dim3(64), dim3(64), 0, stream, w1, b1, ws);
    hipLaunchKernelGGL(m0_kernel, dim3(1), dim3(256), 0, stream, w2, ws);
    hipLaunchKernelGGL(ttt_kernel, dim3(256), dim3(256), 0, stream,
                       seq, w2, b2, outw, outb, ws, out);
}

// Round 6
// 389.093 us; speedup vs baseline: 1.4306x; 1.4306x over previous
//
#include <hip/hip_runtime.h>

#define TSTEPS 1023
#define GAMMA  (0.01f / 32.0f)   // LR * dL/dy scale: 2/(64*2) folded
#define EPSV   1e-5f

typedef float v2f __attribute__((ext_vector_type(2)));
typedef float v4f __attribute__((ext_vector_type(4)));
typedef unsigned int v2u __attribute__((ext_vector_type(2)));

template<int CTRL>
__device__ __forceinline__ float dppmov(float x) {
    return __int_as_float(__builtin_amdgcn_update_dpp(0, __float_as_int(x), CTRL, 0xF, 0xF, true));
}
__device__ __forceinline__ v2u swap16(float a, float b) {
    return __builtin_amdgcn_permlane16_swap(__float_as_uint(a), __float_as_uint(b), false, false);
}
__device__ __forceinline__ v2u swap32(float a, float b) {
    return __builtin_amdgcn_permlane32_swap(__float_as_uint(a), __float_as_uint(b), false, false);
}
__device__ __forceinline__ float rlane(float v, int sl) {
    return __int_as_float(__builtin_amdgcn_readlane(__float_as_int(v), sl));
}
#define U2F(x) __uint_as_float(x)

// ---------------- fully fused kernel ----------------
// R6: hs/Gram/Z0 prep fused as a per-block LDS prologue (each block builds its
// own tables; ~1M MAC, a few us, fully parallel) -- removes 3 kernel launches
// + ~70us fixed overhead measured constant across R0..R3. Main TTT loop is
// byte-identical to R3 (verified 280us): 4-wave j-split, register-resident Z,
// readlane row broadcast, parity ping-pong y-exchange, one barrier/step.
// Prologue numerics mirror the old kernels' accumulation order exactly
// (ascending x / ascending i), LN via DPP row-aligned 16-lane groups.
struct TTTSmem {
    float hs[4096];          // prologue: e-table (et), then hs
    float Gs[4096];          // prologue: e^T (etT), then pre-scaled gram
    int   sq[2048];          // unguarded prefetch reads sq[2048..2049] -> land in ybuf (harmless)
    float ybuf[2][4][64];    // [parity][wave][lane] y-partial exchange
    float ctxp[4][64];       // final ctx partials
    float zbuf[1024];        // Z0 handoff (64 x 16)
    float a1T[8192];         // layer1 activations, transposed [i][w]
    float scratch[8192];     // ffw1 -> ffw2 -> hs^T
};

__device__ __forceinline__ void reduce4(const v2f* a2, const v2f* p2, v2f* dz2) {
    // fold lane bit0: partner lane's slot m^2 is the same logical j
    float q0 = p2[0].x + dppmov<0xB1>(p2[1].x);
    float q1 = p2[0].y + dppmov<0xB1>(p2[1].y);
    // relu mask (slot-aligned)
    float rm0 = (a2[0].x > 0.0f) ? q0 : 0.0f;
    float rm1 = (a2[0].y > 0.0f) ? q1 : 0.0f;
    // fold b4 (encodes q-index into b4) then sum over b5
    v2u f01 = swap16(rm0, rm1);
    float T = U2F(f01[0]) + U2F(f01[1]);        // j = b4 + 2*b0, summed over b4-pair
    v2u g01 = swap32(T, T);
    T = U2F(g01[0]) + U2F(g01[1]);              // summed over b5
    // orbit sums over lane bits 1,2,3
    T = T + dppmov<0x122>(T);   // row_ror:2
    T = T + dppmov<0x124>(T);   // row_ror:4
    T = T + dppmov<0x128>(T);   // row_ror:8
    // broadcast: T = dz[b4 + 2*b0] -> all 4 slots (slot m <-> j = m ^ 2*b0)
    v2u u01 = swap16(T, T);
    const float A0 = U2F(u01[0]);               // dz[0 ^ 2b0] -> slot 0
    const float A1 = U2F(u01[1]);               // dz[1 ^ 2b0] -> slot 1
    dz2[0] = {A0, A1};
    dz2[1] = {dppmov<0xB1>(A0), dppmov<0xB1>(A1)};   // slots 2,3 (other b0)
}

__launch_bounds__(256, 1)
__global__ void ttt_kernel(const int* __restrict__ seq,
                           const float* __restrict__ embed,
                           const float* __restrict__ ffw1, const float* __restrict__ ffb1,
                           const float* __restrict__ ffw2, const float* __restrict__ ffb2,
                           const float* __restrict__ lng,  const float* __restrict__ lnb,
                           const float* __restrict__ w1,   const float* __restrict__ b1,
                           const float* __restrict__ w2,   const float* __restrict__ b2i,
                           const float* __restrict__ outw, const float* __restrict__ outb,
                           float* __restrict__ out) {
    __shared__ TTTSmem sm;

    const int b    = blockIdx.x;
    const int tid  = threadIdx.x;
    const int wv   = tid >> 6;
    const int lane = tid & 63;
    const int b0   = lane & 1;
    const int X    = b0 << 1;              // slot xor: logical j = 4*wv + (slot ^ X)
    const bool pb  = (b0 != 0);
    const bool wv0 = (wv == 0);

    // ======== PROLOGUE ========
    // B0: stage sq, et (hs region), etT (Gs region), ffw1 (scratch)
    {
        int4*       qv = (int4*)sm.sq;
        const int4* qs = (const int4*)(seq + b * 2048);
        qv[tid]       = qs[tid];
        qv[256 + tid] = qs[256 + tid];
        const v4f* e4 = (const v4f*)embed;
#pragma unroll
        for (int p = 0; p < 4; ++p) {
            int i4 = p * 256 + tid;
            v4f v = e4[i4];
            ((v4f*)sm.hs)[i4] = v;                 // et[w][h]
            int w = i4 >> 4, h0 = (i4 & 15) << 2;  // transpose: etT[h][w]
            sm.Gs[(h0 + 0) * 64 + w] = v.x;
            sm.Gs[(h0 + 1) * 64 + w] = v.y;
            sm.Gs[(h0 + 2) * 64 + w] = v.z;
            sm.Gs[(h0 + 3) * 64 + w] = v.w;
        }
        const v4f* f14 = (const v4f*)ffw1;
        v4f* s4 = (v4f*)sm.scratch;
#pragma unroll
        for (int p = 0; p < 8; ++p) s4[p * 256 + tid] = f14[p * 256 + tid];
    }
    __syncthreads();

    // B1: layer1 z1 = ffb1 + e@ffw1, relu -> a1T[i][w]. thread = (g=w-octet, iq=i-quad)
    {
        const int g = tid >> 5, iq = tid & 31;
        v4f bb = *(const v4f*)(ffb1 + 4 * iq);
        v4f acc[8];
#pragma unroll
        for (int ww = 0; ww < 8; ++ww) acc[ww] = bb;
        for (int x = 0; x < 64; ++x) {             // strict ascending x (matches old hs_kernel)
            v4f f  = *(const v4f*)(sm.scratch + x * 128 + 4 * iq);
            v4f ea = *(const v4f*)(sm.Gs + x * 64 + 8 * g);
            v4f eb = *(const v4f*)(sm.Gs + x * 64 + 8 * g + 4);
            acc[0] += ea.x * f; acc[1] += ea.y * f;
            acc[2] += ea.z * f; acc[3] += ea.w * f;
            acc[4] += eb.x * f; acc[5] += eb.y * f;
            acc[6] += eb.z * f; acc[7] += eb.w * f;
        }
#pragma unroll
        for (int ww = 0; ww < 8; ++ww) {
            int w = 8 * g + ww;
#pragma unroll
            for (int ii = 0; ii < 4; ++ii)
                sm.a1T[(4 * iq + ii) * 64 + w] = fmaxf(acc[ww][ii], 0.0f);
        }
    }
    __syncthreads();

    // stage ffw2 -> scratch (overwrites ffw1)
    {
        const v4f* f24 = (const v4f*)ffw2;
        v4f* s4 = (v4f*)sm.scratch;
#pragma unroll
        for (int p = 0; p < 8; ++p) s4[p * 256 + tid] = f24[p * 256 + tid];
    }
    __syncthreads();

    // B3: layer2 f = ffb2 + a1@ffw2; hv = e + f; LN -> hs. thread = (g2=w-quad, hq=h-quad)
    {
        const int g2 = tid >> 4, hq = tid & 15;
        v4f bb = *(const v4f*)(ffb2 + 4 * hq);
        v4f acc[4];
#pragma unroll
        for (int ww = 0; ww < 4; ++ww) acc[ww] = bb;
        for (int i = 0; i < 128; ++i) {            // strict ascending i (matches old hs_kernel)
            v4f f = *(const v4f*)(sm.scratch + i * 64 + 4 * hq);
            v4f a = *(const v4f*)(sm.a1T + i * 64 + 4 * g2);
            acc[0] += a.x * f; acc[1] += a.y * f;
            acc[2] += a.z * f; acc[3] += a.w * f;
        }
        v4f g4 = *(const v4f*)(lng + 4 * hq);
        v4f l4 = *(const v4f*)(lnb + 4 * hq);
#pragma unroll
        for (int ww = 0; ww < 4; ++ww) {
            int w = 4 * g2 + ww;
            v4f ev = *(const v4f*)(sm.hs + w * 64 + 4 * hq);   // et (read before overwrite, same thread)
            v4f hv = ev + acc[ww];
            float ps = (hv.x + hv.y) + (hv.z + hv.w);          // 16-lane group (DPP-row aligned)
            ps += dppmov<0x121>(ps);
            ps += dppmov<0x122>(ps);
            ps += dppmov<0x124>(ps);
            ps += dppmov<0x128>(ps);
            float mu = ps * (1.0f / 64.0f);
            v4f dv = hv - mu;
            float pv = (dv.x * dv.x + dv.y * dv.y) + (dv.z * dv.z + dv.w * dv.w);
            pv += dppmov<0x121>(pv);
            pv += dppmov<0x122>(pv);
            pv += dppmov<0x124>(pv);
            pv += dppmov<0x128>(pv);
            float rstd = 1.0f / sqrtf(pv * (1.0f / 64.0f) + EPSV);
            v4f r = dv * rstd * g4 + l4;
            *(v4f*)(sm.hs + w * 64 + 4 * hq) = r;
        }
    }
    __syncthreads();

    // B4: hsT[x][t] -> scratch (overwrites ffw2)
#pragma unroll
    for (int p = 0; p < 16; ++p) {
        int idx = p * 256 + tid;
        sm.scratch[(idx & 63) * 64 + (idx >> 6)] = sm.hs[idx];
    }
    __syncthreads();

    // B5: gram Gs = GAMMA*(hs@hs^T) + GAMMA; Z0 = b1 + hs@w1 -> zbuf
    {
        const int g3 = tid >> 4, tq = tid & 15;
        v4f acc[4] = {{0,0,0,0},{0,0,0,0},{0,0,0,0},{0,0,0,0}};
        for (int xb = 0; xb < 16; ++xb) {
            v4f hw0 = *(const v4f*)(sm.hs + (4 * g3 + 0) * 64 + 4 * xb);
            v4f hw1 = *(const v4f*)(sm.hs + (4 * g3 + 1) * 64 + 4 * xb);
            v4f hw2 = *(const v4f*)(sm.hs + (4 * g3 + 2) * 64 + 4 * xb);
            v4f hw3 = *(const v4f*)(sm.hs + (4 * g3 + 3) * 64 + 4 * xb);
#pragma unroll
            for (int xx = 0; xx < 4; ++xx) {       // strict ascending x (matches old gz_kernel)
                v4f hT = *(const v4f*)(sm.scratch + (4 * xb + xx) * 64 + 4 * tq);
                acc[0] += hw0[xx] * hT;
                acc[1] += hw1[xx] * hT;
                acc[2] += hw2[xx] * hT;
                acc[3] += hw3[xx] * hT;
            }
        }
#pragma unroll
        for (int ww = 0; ww < 4; ++ww) {
            v4f r = acc[ww] * GAMMA + GAMMA;       // pre-scaled
            *(v4f*)(sm.Gs + (4 * g3 + ww) * 64 + 4 * tq) = r;
        }
        // Z0: lane = token row w, wave = j-quad
        v4f accz = *(const v4f*)(b1 + 4 * wv);
        for (int x = 0; x < 64; ++x) {             // strict ascending x (matches old gz_kernel)
            float hx = sm.scratch[x * 64 + lane];
            v4f w4 = *(const v4f*)(w1 + x * 16 + 4 * wv);
            accz += hx * w4;
        }
        *(v4f*)(sm.zbuf + lane * 16 + 4 * wv) = accz;
    }
    __syncthreads();

    // ======== MAIN LOOP (byte-identical to R3 except Zv init source) ========
    v2f Zv[2];
    {
        v4f z0 = *(const v4f*)(sm.zbuf + lane * 16 + 4 * wv);
        Zv[0] = {z0.x, z0.y};
        Zv[1] = {z0.z, z0.w};
    }

    v2f W2p[2];
#pragma unroll
    for (int i = 0; i < 2; ++i) {
        v2f w;
        w.x = w2[(4 * wv + ((2 * i) ^ X)) * 64 + lane];
        w.y = w2[(4 * wv + ((2 * i + 1) ^ X)) * 64 + lane];
        W2p[i] = w;
    }
    float ybias = wv0 ? b2i[lane] : 0.0f;
    const float gma = wv0 ? GAMMA : 0.0f;

    int tk = sm.sq[0];
    v2f z2[2];
    {
        const int stk = __builtin_amdgcn_readfirstlane(tk);
        const float e0 = rlane(Zv[0].x, stk);
        const float e1 = rlane(Zv[0].y, stk);
        const float e2 = rlane(Zv[1].x, stk);
        const float e3 = rlane(Zv[1].y, stk);
        z2[0] = { pb ? e2 : e0, pb ? e3 : e1 };
        z2[1] = { pb ? e0 : e2, pb ? e1 : e3 };
    }
    float vv = sm.hs[sm.sq[1] * 64 + lane];

    int2 pairT  = *(const int2*)(sm.sq + 2);
    int2 pairT1 = *(const int2*)(sm.sq + 4);

#pragma unroll 2
    for (int t = 0; t < TSTEPS - 1; ++t) {
        const int tkn = pairT.x;
        const int tvn = pairT.y;
        const int par = t & 1;

        const v2f zero2 = {0.0f, 0.0f};
        v2f a2[2];
        a2[0] = __builtin_elementwise_max(z2[0], zero2);
        a2[1] = __builtin_elementwise_max(z2[1], zero2);
        v2f accv = a2[0] * W2p[0] + a2[1] * W2p[1];
        const float ypart = ybias + accv.x + accv.y;

        sm.ybuf[par][wv][lane] = ypart;
        __syncthreads();
        const float y0 = sm.ybuf[par][0][lane];
        const float y1 = sm.ybuf[par][1][lane];
        const float y2 = sm.ybuf[par][2][lane];
        const float y3 = sm.ybuf[par][3][lane];

        const float vnext = sm.hs[tvn * 64 + lane];
        const float cr = sm.Gs[tk * 64 + lane];
        const int2 pairT2 = *(const int2*)(sm.sq + 2 * t + 6);
        const int stkn = __builtin_amdgcn_readfirstlane(tkn);
        const float e0 = rlane(Zv[0].x, stkn);
        const float e1 = rlane(Zv[0].y, stkn);
        const float e2 = rlane(Zv[1].x, stkn);
        const float e3 = rlane(Zv[1].y, stkn);
        const v2f E0 = { pb ? e2 : e0, pb ? e3 : e1 };
        const v2f E1 = { pb ? e0 : e2, pb ? e1 : e3 };
        const float cz = rlane(cr, stkn);

        const float d = ((y0 + y1) + (y2 + y3)) - vv;

        const v2f d2 = {d, d};
        v2f p2[2];
        p2[0] = W2p[0] * d2;
        p2[1] = W2p[1] * d2;
        const float sd = GAMMA * d;
        ybias -= gma * d;
        const v2f sd2 = {sd, sd};
        W2p[0] = W2p[0] - sd2 * a2[0];
        W2p[1] = W2p[1] - sd2 * a2[1];

        v2f dz2[2];
        reduce4(a2, p2, dz2);

        const v2f cz2 = {cz, cz};
        z2[0] = E0 - cz2 * dz2[0];
        z2[1] = E1 - cz2 * dz2[1];

        const v2f dzl0 = pb ? dz2[1] : dz2[0];
        const v2f dzl1 = pb ? dz2[0] : dz2[1];
        const v2f cr2 = {cr, cr};
        Zv[0] = Zv[0] - cr2 * dzl0;
        Zv[1] = Zv[1] - cr2 * dzl1;

        vv = vnext;
        tk = tkn;
        pairT = pairT1;
        pairT1 = pairT2;
    }

    // peeled final step (t = 1022): tkn = query token sq[2047]
    {
        const int tkn = pairT.y;
        const v2f zero2 = {0.0f, 0.0f};
        v2f a2[2];
        a2[0] = __builtin_elementwise_max(z2[0], zero2);
        a2[1] = __builtin_elementwise_max(z2[1], zero2);
        v2f accv = a2[0] * W2p[0] + a2[1] * W2p[1];
        const float ypart = ybias + accv.x + accv.y;

        sm.ybuf[0][wv][lane] = ypart;
        __syncthreads();
        const float y0 = sm.ybuf[0][0][lane];
        const float y1 = sm.ybuf[0][1][lane];
        const float y2 = sm.ybuf[0][2][lane];
        const float y3 = sm.ybuf[0][3][lane];

        const float cr = sm.Gs[tk * 64 + lane];
        const int stkn = __builtin_amdgcn_readfirstlane(tkn);
        const float e0 = rlane(Zv[0].x, stkn);
        const float e1 = rlane(Zv[0].y, stkn);
        const float e2 = rlane(Zv[1].x, stkn);
        const float e3 = rlane(Zv[1].y, stkn);
        const v2f E0 = { pb ? e2 : e0, pb ? e3 : e1 };
        const v2f E1 = { pb ? e0 : e2, pb ? e1 : e3 };
        const float cz = rlane(cr, stkn);

        const float d = ((y0 + y1) + (y2 + y3)) - vv;

        const v2f d2 = {d, d};
        v2f p2[2];
        p2[0] = W2p[0] * d2;
        p2[1] = W2p[1] * d2;
        const float sd = GAMMA * d;
        ybias -= gma * d;
        const v2f sd2 = {sd, sd};
        W2p[0] = W2p[0] - sd2 * a2[0];
        W2p[1] = W2p[1] - sd2 * a2[1];

        v2f dz2[2];
        reduce4(a2, p2, dz2);

        const v2f cz2 = {cz, cz};
        z2[0] = E0 - cz2 * dz2[0];
        z2[1] = E1 - cz2 * dz2[1];
    }

    // final eval + output matvec
    {
        const v2f zero2 = {0.0f, 0.0f};
        v2f acc = __builtin_elementwise_max(z2[0], zero2) * W2p[0]
                + __builtin_elementwise_max(z2[1], zero2) * W2p[1];
        sm.ctxp[wv][lane] = ybias + acc.x + acc.y;
    }
    __syncthreads();
    if (wv0) {
        float o = outb[lane];
        for (int hh = 0; hh < 64; ++hh)
            o += (sm.ctxp[0][hh] + sm.ctxp[1][hh] + sm.ctxp[2][hh] + sm.ctxp[3][hh])
                 * outw[hh * 64 + lane];
        out[b * 64 + lane] = o;
    }
}

// ---------------- launcher: single kernel ----------------
extern "C" void kernel_launch(void* const* d_in, const int* in_sizes, int n_in,
                              void* d_out, int out_size, void* d_ws, size_t ws_size,
                              hipStream_t stream) {
    const int*   seq   = (const int*)d_in[0];
    const float* embed = (const float*)d_in[1];
    const float* ffw1  = (const float*)d_in[2];
    const float* ffb1  = (const float*)d_in[3];
    const float* ffw2  = (const float*)d_in[4];
    const float* ffb2  = (const float*)d_in[5];
    const float* lng   = (const float*)d_in[6];
    const float* lnb   = (const float*)d_in[7];
    const float* w1    = (const float*)d_in[8];
    const float* b1    = (const float*)d_in[9];
    const float* w2    = (const float*)d_in[10];
    const float* b2    = (const float*)d_in[11];
    const float* outw  = (const float*)d_in[12];
    const float* outb  = (const float*)d_in[13];
    float* out = (float*)d_out;

    hipLaunchKernelGGL(ttt_kernel, dim3(256), dim3(256), 0, stream,
                       seq, embed, ffw1, ffb1, ffw2, ffb2, lng, lnb,
                       w1, b1, w2, b2, outw, outb, out);
}

// Round 7
// 368.635 us; speedup vs baseline: 1.5100x; 1.0555x over previous
//
#include <hip/hip_runtime.h>

#define TSTEPS 1023
#define GAMMA  (0.01f / 32.0f)   // LR * dL/dy scale: 2/(64*2) folded
#define EPSV   1e-5f

// workspace layout (float offsets)
#define WS_HS 0       // 64*64 hs table
#define WS_G  4096    // 64*64 PRE-SCALED gram: Gs = GAMMA*G + GAMMA
#define WS_Z0 8192    // 64*16 initial Ztilde = hs@w1 + b1

typedef float v2f __attribute__((ext_vector_type(2)));
typedef float v4f __attribute__((ext_vector_type(4)));
typedef unsigned int v2u __attribute__((ext_vector_type(2)));

template<int CTRL>
__device__ __forceinline__ float dppmov(float x) {
    return __int_as_float(__builtin_amdgcn_update_dpp(0, __float_as_int(x), CTRL, 0xF, 0xF, true));
}
__device__ __forceinline__ v2u swap16(float a, float b) {
    return __builtin_amdgcn_permlane16_swap(__float_as_uint(a), __float_as_uint(b), false, false);
}
__device__ __forceinline__ v2u swap32(float a, float b) {
    return __builtin_amdgcn_permlane32_swap(__float_as_uint(a), __float_as_uint(b), false, false);
}
__device__ __forceinline__ float rlane(float v, int sl) {
    return __int_as_float(__builtin_amdgcn_readlane(__float_as_int(v), sl));
}
#define U2F(x) __uint_as_float(x)

// ---------------- kernel A: hs table (per-token embed->FFN->LN), 64 blocks ----------------
__global__ void hs_kernel(const float* __restrict__ embed,
                          const float* __restrict__ ffw1, const float* __restrict__ ffb1,
                          const float* __restrict__ ffw2, const float* __restrict__ ffb2,
                          const float* __restrict__ lng,  const float* __restrict__ lnb,
                          float* __restrict__ ws) {
    __shared__ float e[64];
    __shared__ float a1[128];
    int w = blockIdx.x;
    int tid = threadIdx.x;
    if (tid < 64) e[tid] = embed[w * 64 + tid];
    __syncthreads();
    float z1 = ffb1[tid];
    for (int x = 0; x < 64; ++x) z1 += e[x] * ffw1[x * 128 + tid];
    a1[tid] = fmaxf(z1, 0.0f);
    __syncthreads();
    if (tid < 64) {
        float f = ffb2[tid];
        for (int i = 0; i < 128; ++i) f += a1[i] * ffw2[i * 64 + tid];
        float hv = e[tid] + f;
        float s = hv;
#pragma unroll
        for (int m = 32; m >= 1; m >>= 1) s += __shfl_xor(s, m);
        float mu = s * (1.0f / 64.0f);
        float dv = hv - mu;
        float vs = dv * dv;
#pragma unroll
        for (int m = 32; m >= 1; m >>= 1) vs += __shfl_xor(vs, m);
        float rstd = 1.0f / sqrtf(vs * (1.0f / 64.0f) + EPSV);
        ws[WS_HS + w * 64 + tid] = dv * rstd * lng[tid] + lnb[tid];
    }
}

// ---------------- kernel B: pre-scaled Gram + Ztilde0, 64 blocks ----------------
__global__ void gz_kernel(const float* __restrict__ w1, const float* __restrict__ b1,
                          float* __restrict__ ws) {
    __shared__ float row[64];
    int w = blockIdx.x, tid = threadIdx.x;
    row[tid] = ws[WS_HS + w * 64 + tid];
    __syncthreads();
    float g = 0.0f;
    for (int x = 0; x < 64; ++x) g += row[x] * ws[WS_HS + tid * 64 + x];
    ws[WS_G + w * 64 + tid] = GAMMA * g + GAMMA;      // pre-scaled
    if (tid < 16) {
        float z = b1[tid];
        for (int x = 0; x < 64; ++x) z += row[x] * w1[x * 16 + tid];
        ws[WS_Z0 + w * 16 + tid] = z;
    }
}

// ---------------- main kernel: 4-wave j-split, register Z, THIN POST-BARRIER BURST ----------------
// R7 (on top of verified R3): (1) y-exchange laid out [lane][wave] so each
// wave reads all 4 partials with ONE ds_read_b128 (write side is an 8-way
// scatter, ~+11cy on-chain; read side one latency event + 12cy pipe instead
// of 4 queued b32s); (2) cr row prefetched one step ahead (token known from
// pairT) so cz = readlane(cr,...) is register-immediate and the only
// this-step-critical LDS op post-barrier is the single y b128 read, issued
// first. d stays bitwise identical across waves (same 4 floats, same order,
// fixed tree). Everything else identical to R3.
struct TTT4Smem {
    float hs[4096];
    float Gs[4096];
    int   sq[2048];                 // unguarded prefetch reads sq[2048..2049] -> land in ybuf (harmless)
    float ybuf[2][64][4];           // [parity][lane][wave] y-partial exchange (b128-readable)
    float ctxp[4][64];              // final ctx partials
};

__device__ __forceinline__ void reduce4(const v2f* a2, const v2f* p2, v2f* dz2) {
    // fold lane bit0: partner lane's slot m^2 is the same logical j
    float q0 = p2[0].x + dppmov<0xB1>(p2[1].x);
    float q1 = p2[0].y + dppmov<0xB1>(p2[1].y);
    // relu mask (slot-aligned)
    float rm0 = (a2[0].x > 0.0f) ? q0 : 0.0f;
    float rm1 = (a2[0].y > 0.0f) ? q1 : 0.0f;
    // fold b4 (encodes q-index into b4) then sum over b5
    v2u f01 = swap16(rm0, rm1);
    float T = U2F(f01[0]) + U2F(f01[1]);        // j = b4 + 2*b0, summed over b4-pair
    v2u g01 = swap32(T, T);
    T = U2F(g01[0]) + U2F(g01[1]);              // summed over b5
    // orbit sums over lane bits 1,2,3
    T = T + dppmov<0x122>(T);   // row_ror:2
    T = T + dppmov<0x124>(T);   // row_ror:4
    T = T + dppmov<0x128>(T);   // row_ror:8
    // broadcast: T = dz[b4 + 2*b0] -> all 4 slots (slot m <-> j = m ^ 2*b0)
    v2u u01 = swap16(T, T);
    const float A0 = U2F(u01[0]);               // dz[0 ^ 2b0] -> slot 0
    const float A1 = U2F(u01[1]);               // dz[1 ^ 2b0] -> slot 1
    dz2[0] = {A0, A1};
    dz2[1] = {dppmov<0xB1>(A0), dppmov<0xB1>(A1)};   // slots 2,3 (other b0)
}

__launch_bounds__(256, 1)
__global__ void ttt_kernel(const int* __restrict__ seq,
                           const float* __restrict__ w2, const float* __restrict__ b2i,
                           const float* __restrict__ outw, const float* __restrict__ outb,
                           const float* __restrict__ ws, float* __restrict__ out) {
    __shared__ TTT4Smem sm;

    const int b    = blockIdx.x;
    const int tid  = threadIdx.x;
    const int wv   = tid >> 6;
    const int lane = tid & 63;
    const int b0   = lane & 1;
    const int X    = b0 << 1;              // slot xor: logical j = 4*wv + (slot ^ X)
    const bool pb  = (b0 != 0);
    const bool wv0 = (wv == 0);

    {   // vectorized staging (256 threads)
        float4*       hv = (float4*)sm.hs;
        const float4* sv = (const float4*)(ws + WS_HS);
#pragma unroll
        for (int m = 0; m < 4; ++m) hv[m * 256 + tid] = sv[m * 256 + tid];
        float4*       gv = (float4*)sm.Gs;
        const float4* gs = (const float4*)(ws + WS_G);
#pragma unroll
        for (int m = 0; m < 4; ++m) gv[m * 256 + tid] = gs[m * 256 + tid];
        int4*       qv = (int4*)sm.sq;
        const int4* qs = (const int4*)(seq + b * 2048);
#pragma unroll
        for (int m = 0; m < 2; ++m) qv[m * 256 + tid] = qs[m * 256 + tid];
    }

    // Z state: row = lane, this wave's 4 j-columns, LOGICAL order, registers only
    v2f Zv[2];
    {
        const float4 z0 = *(const float4*)(ws + WS_Z0 + lane * 16 + 4 * wv);
        Zv[0] = {z0.x, z0.y};
        Zv[1] = {z0.z, z0.w};
    }

    // W2 in permuted slot order for this wave's j-slice
    v2f W2p[2];
#pragma unroll
    for (int i = 0; i < 2; ++i) {
        v2f w;
        w.x = w2[(4 * wv + ((2 * i) ^ X)) * 64 + lane];
        w.y = w2[(4 * wv + ((2 * i + 1) ^ X)) * 64 + lane];
        W2p[i] = w;
    }
    float ybias = wv0 ? b2i[lane] : 0.0f;     // b2 lives in wave0's y-partial only
    const float gma = wv0 ? GAMMA : 0.0f;
    __syncthreads();

    // z2 init: row sq[0] broadcast from registers via readlane, permuted slots
    int tk = sm.sq[0];
    v2f z2[2];
    {
        const int stk = __builtin_amdgcn_readfirstlane(tk);
        const float e0 = rlane(Zv[0].x, stk);
        const float e1 = rlane(Zv[0].y, stk);
        const float e2 = rlane(Zv[1].x, stk);
        const float e3 = rlane(Zv[1].y, stk);
        z2[0] = { pb ? e2 : e0, pb ? e3 : e1 };
        z2[1] = { pb ? e0 : e2, pb ? e1 : e3 };
    }
    float vv = sm.hs[sm.sq[1] * 64 + lane];
    float cr = sm.Gs[tk * 64 + lane];            // row tk, pre-scaled gamma*(G+1)

    int2 pairT  = *(const int2*)(sm.sq + 2);
    int2 pairT1 = *(const int2*)(sm.sq + 4);

    // main loop: steps 0..1021 (last step peeled)
#pragma unroll 2
    for (int t = 0; t < TSTEPS - 1; ++t) {
        const int tkn = pairT.x;
        const int tvn = pairT.y;
        const int par = t & 1;

        // ---- forward on own j-slice ----
        const v2f zero2 = {0.0f, 0.0f};
        v2f a2[2];
        a2[0] = __builtin_elementwise_max(z2[0], zero2);
        a2[1] = __builtin_elementwise_max(z2[1], zero2);
        v2f accv = a2[0] * W2p[0] + a2[1] * W2p[1];
        const float ypart = ybias + accv.x + accv.y;

        // ---- y exchange (parity ping-pong, one barrier per step) ----
        sm.ybuf[par][lane][wv] = ypart;           // 8-way scatter write (bounded, on-chain +~11cy)
        __syncthreads();
        // critical read FIRST: all 4 partials in one b128
        const v4f yv = *(const v4f*)sm.ybuf[par][lane];
        // next-step prefetches (consumed next iteration; drain in this step's shadow)
        const float vnext = sm.hs[tvn * 64 + lane];
        const float crn   = sm.Gs[tkn * 64 + lane];
        const int2 pairT2 = *(const int2*)(sm.sq + 2 * t + 6);  // t=1021 reads ybuf: unused

        // ---- register-Z row broadcast + cz (all register ops; cr carried) ----
        const int stkn = __builtin_amdgcn_readfirstlane(tkn);
        const float e0 = rlane(Zv[0].x, stkn);      // Zv current through t-1
        const float e1 = rlane(Zv[0].y, stkn);
        const float e2 = rlane(Zv[1].x, stkn);
        const float e3 = rlane(Zv[1].y, stkn);
        const v2f E0 = { pb ? e2 : e0, pb ? e3 : e1 };   // permuted slot order
        const v2f E1 = { pb ? e0 : e2, pb ? e1 : e3 };
        const float cz = rlane(cr, stkn);           // Gs[tk*64 + tkn]

        // ---- d (fixed tree -> bitwise identical in all 4 waves) ----
        const float d = ((yv.x + yv.y) + (yv.z + yv.w)) - vv;

        // ---- p (pre-update W2) + local W2/b2 update ----
        const v2f d2 = {d, d};
        v2f p2[2];
        p2[0] = W2p[0] * d2;
        p2[1] = W2p[1] * d2;
        const float sd = GAMMA * d;
        ybias -= gma * d;
        const v2f sd2 = {sd, sd};
        W2p[0] = W2p[0] - sd2 * a2[0];
        W2p[1] = W2p[1] - sd2 * a2[1];

        // ---- cross-lane reduction + broadcast ----
        v2f dz2[2];
        reduce4(a2, p2, dz2);

        // ---- next-token state (table lag covered by cz term) ----
        const v2f cz2 = {cz, cz};
        z2[0] = E0 - cz2 * dz2[0];
        z2[1] = E1 - cz2 * dz2[1];

        // ---- prompt register-Z update (logical order) ----
        const v2f dzl0 = pb ? dz2[1] : dz2[0];
        const v2f dzl1 = pb ? dz2[0] : dz2[1];
        const v2f cr2 = {cr, cr};
        Zv[0] = Zv[0] - cr2 * dzl0;
        Zv[1] = Zv[1] - cr2 * dzl1;

        vv = vnext;
        cr = crn;
        tk = tkn;
        pairT = pairT1;
        pairT1 = pairT2;
    }

    // ---- peeled final step (t = 1022): tkn = query token sq[2047] ----
    {
        const int tkn = pairT.y;                  // pairT = {sq[2046], sq[2047]}
        const v2f zero2 = {0.0f, 0.0f};
        v2f a2[2];
        a2[0] = __builtin_elementwise_max(z2[0], zero2);
        a2[1] = __builtin_elementwise_max(z2[1], zero2);
        v2f accv = a2[0] * W2p[0] + a2[1] * W2p[1];
        const float ypart = ybias + accv.x + accv.y;

        sm.ybuf[0][lane][wv] = ypart;             // 1022 even -> parity 0
        __syncthreads();
        const v4f yv = *(const v4f*)sm.ybuf[0][lane];

        const int stkn = __builtin_amdgcn_readfirstlane(tkn);
        const float e0 = rlane(Zv[0].x, stkn);    // Zv current through step 1021
        const float e1 = rlane(Zv[0].y, stkn);
        const float e2 = rlane(Zv[1].x, stkn);
        const float e3 = rlane(Zv[1].y, stkn);
        const v2f E0 = { pb ? e2 : e0, pb ? e3 : e1 };
        const v2f E1 = { pb ? e0 : e2, pb ? e1 : e3 };
        const float cz = rlane(cr, stkn);

        const float d = ((yv.x + yv.y) + (yv.z + yv.w)) - vv;

        const v2f d2 = {d, d};
        v2f p2[2];
        p2[0] = W2p[0] * d2;
        p2[1] = W2p[1] * d2;
        const float sd = GAMMA * d;
        ybias -= gma * d;
        const v2f sd2 = {sd, sd};
        W2p[0] = W2p[0] - sd2 * a2[0];
        W2p[1] = W2p[1] - sd2 * a2[1];

        v2f dz2[2];
        reduce4(a2, p2, dz2);

        const v2f cz2 = {cz, cz};
        z2[0] = E0 - cz2 * dz2[0];
        z2[1] = E1 - cz2 * dz2[1];
    }

    // ---- final eval: ctx partial per wave, combine, then out matvec ----
    {
        const v2f zero2 = {0.0f, 0.0f};
        v2f acc = __builtin_elementwise_max(z2[0], zero2) * W2p[0]
                + __builtin_elementwise_max(z2[1], zero2) * W2p[1];
        sm.ctxp[wv][lane] = ybias + acc.x + acc.y;
    }
    __syncthreads();
    if (wv0) {
        float o = outb[lane];
        for (int hh = 0; hh < 64; ++hh)
            o += (sm.ctxp[0][hh] + sm.ctxp[1][hh] + sm.ctxp[2][hh] + sm.ctxp[3][hh])
                 * outw[hh * 64 + lane];
        out[b * 64 + lane] = o;
    }
}

// ---------------- launcher ----------------
extern "C" void kernel_launch(void* const* d_in, const int* in_sizes, int n_in,
                              void* d_out, int out_size, void* d_ws, size_t ws_size,
                              hipStream_t stream) {
    const int*   seq   = (const int*)d_in[0];
    const float* embed = (const float*)d_in[1];
    const float* ffw1  = (const float*)d_in[2];
    const float* ffb1  = (const float*)d_in[3];
    const float* ffw2  = (const float*)d_in[4];
    const float* ffb2  = (const float*)d_in[5];
    const float* lng   = (const float*)d_in[6];
    const float* lnb   = (const float*)d_in[7];
    const float* w1    = (const float*)d_in[8];
    const float* b1    = (const float*)d_in[9];
    const float* w2    = (const float*)d_in[10];
    const float* b2    = (const float*)d_in[11];
    const float* outw  = (const float*)d_in[12];
    const float* outb  = (const float*)d_in[13];
    float* ws  = (float*)d_ws;
    float* out = (float*)d_out;

    hipLaunchKernelGGL(hs_kernel, dim3(64), dim3(128), 0, stream,
                       embed, ffw1, ffb1, ffw2, ffb2, lng, lnb, ws);
    hipLaunchKernelGGL(gz_kernel, dim3(64), dim3(64), 0, stream, w1, b1, ws);
    hipLaunchKernelGGL(ttt_kernel, dim3(256), dim3(64 * 4), 0, stream,
                       seq, w2, b2, outw, outb, ws, out);
}